// Round 2
// baseline (4080.969 us; speedup 1.0000x reference)
//
#include <hip/hip_runtime.h>

constexpr int C    = 256;    // MODEL_DIM
constexpr int HID  = 128;    // demand-MLP hidden
constexpr int P    = 32768;  // H*W
constexpr int NCOL = 4;
constexpr int NH   = 8;
constexpr int BP   = 16;     // pixels per block
constexpr int R    = 4;      // output channels per thread
constexpr int PT   = 4;      // pixels per thread

// acc[r][pi] += sum_j W[(r*64+tc)*K + j] * X[j][p0+pi]
template <int K>
__device__ __forceinline__ void mat_frag(const float* __restrict__ W,
                                         float (*X)[BP], int tc, int p0,
                                         float acc[R][PT]) {
    for (int j4 = 0; j4 < K / 4; ++j4) {
        float4 w[R];
#pragma unroll
        for (int r = 0; r < R; ++r)
            w[r] = *reinterpret_cast<const float4*>(W + (size_t)(r * 64 + tc) * K + j4 * 4);
#pragma unroll
        for (int j = 0; j < 4; ++j) {
            const float4 x4 = *reinterpret_cast<const float4*>(&X[j4 * 4 + j][p0]);
            const float xs[4] = {x4.x, x4.y, x4.z, x4.w};
#pragma unroll
            for (int r = 0; r < R; ++r) {
                const float wr = (j == 0) ? w[r].x : (j == 1) ? w[r].y : (j == 2) ? w[r].z : w[r].w;
#pragma unroll
                for (int pi = 0; pi < PT; ++pi)
                    acc[r][pi] += wr * xs[pi];
            }
        }
    }
}

__device__ __forceinline__ void load_tile(const float* __restrict__ src, int t,
                                          int pix0, float (*X)[BP]) {
    float4 a = *reinterpret_cast<const float4*>(src + (size_t)t * P + pix0 + 0);
    float4 b = *reinterpret_cast<const float4*>(src + (size_t)t * P + pix0 + 4);
    float4 c = *reinterpret_cast<const float4*>(src + (size_t)t * P + pix0 + 8);
    float4 d = *reinterpret_cast<const float4*>(src + (size_t)t * P + pix0 + 12);
    float* row = X[t];
    *reinterpret_cast<float4*>(row + 0)  = a;
    *reinterpret_cast<float4*>(row + 4)  = b;
    *reinterpret_cast<float4*>(row + 8)  = c;
    *reinterpret_cast<float4*>(row + 12) = d;
}

__global__ __launch_bounds__(256, 2) void fused_dca_kernel(
    const float* __restrict__ ego, const float* __restrict__ dem,
    const float* __restrict__ col,
    const float* __restrict__ w_d1, const float* __restrict__ b_d1,
    const float* __restrict__ w_d2, const float* __restrict__ b_d2,
    const float* __restrict__ wq, const float* __restrict__ bq,
    const float* __restrict__ wk, const float* __restrict__ bk,
    const float* __restrict__ wv, const float* __restrict__ bv,
    const float* __restrict__ wo, const float* __restrict__ bo,
    const float* __restrict__ pos, float* __restrict__ out)
{
    __shared__ __align__(16) float sh_x[C][BP];          // staged activations
    __shared__ __align__(16) float sh_h1[HID][BP];
    __shared__ __align__(16) float sh_d[3][BP];
    __shared__ __align__(16) float sh_sc[NCOL][NH][BP];  // scores -> attn weights

    const int t    = threadIdx.x;
    const int tc   = t & 63;   // channel lane: channels tc, tc+64, tc+128, tc+192
    const int pg   = t >> 6;   // pixel group 0..3 (wave-uniform)
    const int p0   = pg * PT;
    const int pix0 = blockIdx.x * BP;
    const int m_lo = tc >> 5;  // head parity within a channel group

    // ---- demand tile ----
    if (t < 3 * BP) {
        int ci = t / BP, pi = t % BP;
        sh_d[ci][pi] = dem[ci * P + pix0 + pi];
    }
    __syncthreads();

    // ---- h1 = relu(w_d1 @ d + b_d1) ----
    if (t < HID) {
        float w0 = w_d1[t * 3 + 0];
        float w1 = w_d1[t * 3 + 1];
        float w2 = w_d1[t * 3 + 2];
        float bb = b_d1[t];
#pragma unroll
        for (int p = 0; p < BP; ++p) {
            float h = bb + w0 * sh_d[0][p] + w1 * sh_d[1][p] + w2 * sh_d[2][p];
            sh_h1[t][p] = fmaxf(h, 0.0f);
        }
    }
    __syncthreads();

    // ---- qs = ego + pos + (w_d2 @ h1 + b_d2) ----
    {
        float acc[R][PT];
#pragma unroll
        for (int r = 0; r < R; ++r) {
            float bb = b_d2[r * 64 + tc];
#pragma unroll
            for (int pi = 0; pi < PT; ++pi) acc[r][pi] = bb;
        }
        mat_frag<HID>(w_d2, sh_h1, tc, p0, acc);
#pragma unroll
        for (int r = 0; r < R; ++r) {
            int c = r * 64 + tc;
#pragma unroll
            for (int pi = 0; pi < PT; ++pi) {
                int p = p0 + pi;
                float e  = ego[(size_t)c * P + pix0 + p];
                float pe = pos[(size_t)c * P + pix0 + p];
                sh_x[c][p] = acc[r][pi] + e + pe;
            }
        }
    }
    __syncthreads();

    // ---- q = wq @ qs + bq  (registers) ----
    float qreg[R][PT];
    {
#pragma unroll
        for (int r = 0; r < R; ++r) {
            float bb = bq[r * 64 + tc];
#pragma unroll
            for (int pi = 0; pi < PT; ++pi) qreg[r][pi] = bb;
        }
        mat_frag<C>(wq, sh_x, tc, p0, qreg);
    }

    // ---- pass A: scores[n][m][p] = (q . k_n) / sqrt(32) ----
    const float inv_scale = 0.17677669529663687f;  // 1/sqrt(32)
    for (int n = 0; n < NCOL; ++n) {
        __syncthreads();
        load_tile(col + (size_t)n * C * P, t, pix0, sh_x);
        __syncthreads();
        float acc[R][PT];
#pragma unroll
        for (int r = 0; r < R; ++r) {
            float bb = bk[r * 64 + tc];
#pragma unroll
            for (int pi = 0; pi < PT; ++pi) acc[r][pi] = bb;
        }
        mat_frag<C>(wk, sh_x, tc, p0, acc);
#pragma unroll
        for (int r = 0; r < R; ++r)
#pragma unroll
            for (int pi = 0; pi < PT; ++pi) {
                float s = acc[r][pi] * qreg[r][pi];
                s += __shfl_xor(s, 16);
                s += __shfl_xor(s, 8);
                s += __shfl_xor(s, 4);
                s += __shfl_xor(s, 2);
                s += __shfl_xor(s, 1);
                if ((tc & 31) == 0) sh_sc[n][r * 2 + m_lo][p0 + pi] = s * inv_scale;
            }
    }
    __syncthreads();

    // ---- softmax over n per (head, pixel) ----
    if (t < NH * BP) {
        int mm = t / BP, p = t % BP;
        float s0 = sh_sc[0][mm][p], s1 = sh_sc[1][mm][p];
        float s2 = sh_sc[2][mm][p], s3 = sh_sc[3][mm][p];
        float mx = fmaxf(fmaxf(s0, s1), fmaxf(s2, s3));
        float e0 = __expf(s0 - mx), e1 = __expf(s1 - mx);
        float e2 = __expf(s2 - mx), e3 = __expf(s3 - mx);
        float inv = 1.0f / (e0 + e1 + e2 + e3);
        sh_sc[0][mm][p] = e0 * inv;
        sh_sc[1][mm][p] = e1 * inv;
        sh_sc[2][mm][p] = e2 * inv;
        sh_sc[3][mm][p] = e3 * inv;
    }
    __syncthreads();

    // ---- pass B: ao = sum_n attn[n] * v_n ----
    float oacc[R][PT];
#pragma unroll
    for (int r = 0; r < R; ++r)
#pragma unroll
        for (int pi = 0; pi < PT; ++pi) oacc[r][pi] = 0.0f;
    for (int n = 0; n < NCOL; ++n) {
        __syncthreads();
        load_tile(col + (size_t)n * C * P, t, pix0, sh_x);
        __syncthreads();
        float acc[R][PT];
#pragma unroll
        for (int r = 0; r < R; ++r) {
            float bb = bv[r * 64 + tc];
#pragma unroll
            for (int pi = 0; pi < PT; ++pi) acc[r][pi] = bb;
        }
        mat_frag<C>(wv, sh_x, tc, p0, acc);
#pragma unroll
        for (int r = 0; r < R; ++r) {
            int mm = r * 2 + m_lo;
#pragma unroll
            for (int pi = 0; pi < PT; ++pi)
                oacc[r][pi] += sh_sc[n][mm][p0 + pi] * acc[r][pi];
        }
    }
    __syncthreads();

    // ---- stage attention output, final o-projection ----
#pragma unroll
    for (int r = 0; r < R; ++r)
#pragma unroll
        for (int pi = 0; pi < PT; ++pi)
            sh_x[r * 64 + tc][p0 + pi] = oacc[r][pi];
    __syncthreads();
    {
        float acc[R][PT];
#pragma unroll
        for (int r = 0; r < R; ++r) {
            float bb = bo[r * 64 + tc];
#pragma unroll
            for (int pi = 0; pi < PT; ++pi) acc[r][pi] = bb;
        }
        mat_frag<C>(wo, sh_x, tc, p0, acc);
#pragma unroll
        for (int r = 0; r < R; ++r) {
            int c = r * 64 + tc;
#pragma unroll
            for (int pi = 0; pi < PT; ++pi)
                out[(size_t)c * P + pix0 + p0 + pi] = acc[r][pi];
        }
    }
}

extern "C" void kernel_launch(void* const* d_in, const int* in_sizes, int n_in,
                              void* d_out, int out_size, void* d_ws, size_t ws_size,
                              hipStream_t stream) {
    const float* ego  = (const float*)d_in[0];
    const float* dem  = (const float*)d_in[1];
    const float* col  = (const float*)d_in[2];
    const float* w_d1 = (const float*)d_in[3];
    const float* b_d1 = (const float*)d_in[4];
    const float* w_d2 = (const float*)d_in[5];
    const float* b_d2 = (const float*)d_in[6];
    const float* wq   = (const float*)d_in[7];
    const float* bq   = (const float*)d_in[8];
    const float* wk   = (const float*)d_in[9];
    const float* bk   = (const float*)d_in[10];
    const float* wv   = (const float*)d_in[11];
    const float* bv   = (const float*)d_in[12];
    const float* wo   = (const float*)d_in[13];
    const float* bo   = (const float*)d_in[14];
    const float* pos  = (const float*)d_in[15];
    float* out = (float*)d_out;

    dim3 grid(P / BP), block(256);
    hipLaunchKernelGGL(fused_dca_kernel, grid, block, 0, stream,
                       ego, dem, col, w_d1, b_d1, w_d2, b_d2,
                       wq, bq, wk, bk, wv, bv, wo, bo, pos, out);
}

// Round 3
// 574.901 us; speedup vs baseline: 7.0986x; 7.0986x over previous
//
#include <hip/hip_runtime.h>

typedef __attribute__((ext_vector_type(8))) short short8;
typedef __attribute__((ext_vector_type(4))) float f32x4;

constexpr int C   = 256;     // MODEL_DIM
constexpr int HID = 128;
constexpr int P   = 32768;   // H*W
constexpr int BN  = 64;      // pixels per block
constexpr int XLD = 272;     // xT row length (bf16): 256+16 -> 544B rows, 16B aligned
constexpr int HLD = 136;     // h1T row length: 128+8 -> 272B rows, 16B aligned

// ws layout (ushort/bf16 elements)
constexpr unsigned OFF_WQ  = 0;
constexpr unsigned OFF_WK  = 65536;
constexpr unsigned OFF_WV  = 131072;
constexpr unsigned OFF_WO  = 196608;
constexpr unsigned OFF_WD2 = 262144;
constexpr unsigned W_TOTAL = 294912;

__device__ __forceinline__ unsigned short f2b(float x) {     // f32 -> bf16 bits (RNE)
    unsigned u = __float_as_uint(x);
    return (unsigned short)((u + 0x7FFFu + ((u >> 16) & 1u)) >> 16);
}
__device__ __forceinline__ float b2f(unsigned u) {           // bf16 bits (low 16) -> f32
    return __uint_as_float(u << 16);
}

__global__ void cvt_weights(const float* __restrict__ wq, const float* __restrict__ wk,
                            const float* __restrict__ wv, const float* __restrict__ wo,
                            const float* __restrict__ wd2, unsigned short* __restrict__ dst) {
    unsigned i = blockIdx.x * 256 + threadIdx.x;
    if (i >= W_TOTAL) return;
    float v;
    if (i < OFF_WK)       v = wq[i];
    else if (i < OFF_WV)  v = wk[i - OFF_WK];
    else if (i < OFF_WO)  v = wv[i - OFF_WV];
    else if (i < OFF_WD2) v = wo[i - OFF_WO];
    else                  v = wd2[i - OFF_WD2];
    dst[i] = f2b(v);
}

// C[m][n] += sum_k W[m][k] * X[n][k]  (gemm_bt: both operands row-major over k)
template <int K, int LD>
__device__ __forceinline__ void gemm16(const unsigned short* __restrict__ W,
                                       const unsigned short (&B)[BN][LD],
                                       int w, int a, int q, f32x4 (&acc)[4][4]) {
#pragma unroll
    for (int ks = 0; ks < K / 32; ++ks) {
        const int kb = ks * 32 + q * 8;
        short8 af[4], bf[4];
#pragma unroll
        for (int mi = 0; mi < 4; ++mi)
            af[mi] = *reinterpret_cast<const short8*>(W + (size_t)(w * 64 + mi * 16 + a) * K + kb);
#pragma unroll
        for (int ni = 0; ni < 4; ++ni)
            bf[ni] = *reinterpret_cast<const short8*>(&B[ni * 16 + a][kb]);
#pragma unroll
        for (int mi = 0; mi < 4; ++mi)
#pragma unroll
            for (int ni = 0; ni < 4; ++ni)
                acc[mi][ni] = __builtin_amdgcn_mfma_f32_16x16x32_bf16(af[mi], bf[ni], acc[mi][ni], 0, 0, 0);
    }
}

// stage f32 [C][P] tile (optionally sum of two sources) -> bf16 pixel-major LDS
template <bool ADD, int LD>
__device__ __forceinline__ void stage_tile(const float* __restrict__ s0,
                                           const float* __restrict__ s1,
                                           int t, int pix0, unsigned short (&X)[BN][LD]) {
    const int c0 = 2 * (t >> 4);  // even channel 0..30
    const int pb = 4 * (t & 15);  // pixel base 0..60
#pragma unroll
    for (int k = 0; k < 8; ++k) {
        const int c = c0 + 32 * k;
        float4 ra = *reinterpret_cast<const float4*>(s0 + (size_t)c * P + pix0 + pb);
        float4 rb = *reinterpret_cast<const float4*>(s0 + (size_t)(c + 1) * P + pix0 + pb);
        if constexpr (ADD) {
            float4 ta = *reinterpret_cast<const float4*>(s1 + (size_t)c * P + pix0 + pb);
            float4 tb = *reinterpret_cast<const float4*>(s1 + (size_t)(c + 1) * P + pix0 + pb);
            ra.x += ta.x; ra.y += ta.y; ra.z += ta.z; ra.w += ta.w;
            rb.x += tb.x; rb.y += tb.y; rb.z += tb.z; rb.w += tb.w;
        }
        const float va[4] = {ra.x, ra.y, ra.z, ra.w};
        const float vb[4] = {rb.x, rb.y, rb.z, rb.w};
#pragma unroll
        for (int pi = 0; pi < 4; ++pi) {
            unsigned pk = (unsigned)f2b(va[pi]) | ((unsigned)f2b(vb[pi]) << 16);
            *reinterpret_cast<unsigned*>(&X[pb + pi][c]) = pk;
        }
    }
}

__global__ __launch_bounds__(256, 2) void dca_mfma(
    const float* __restrict__ ego, const float* __restrict__ dem,
    const float* __restrict__ col,
    const float* __restrict__ w_d1, const float* __restrict__ b_d1,
    const float* __restrict__ b_d2, const float* __restrict__ bq,
    const float* __restrict__ bk, const float* __restrict__ bv,
    const float* __restrict__ bo, const float* __restrict__ pos,
    const unsigned short* __restrict__ wbf, float* __restrict__ out)
{
    __shared__ __align__(16) unsigned short xT[BN][XLD];
    __shared__ __align__(16) unsigned short h1T[BN][HLD];

    const int t = threadIdx.x;
    const int w = t >> 6;    // wave id -> output rows [64w, 64w+64)
    const int l = t & 63;
    const int a = l & 15;    // row/col within 16-tile
    const int q = l >> 4;    // quad
    const int pix0 = blockIdx.x * BN;

    // ---- P1a: stage bf16(ego + pos) into xT ----
    stage_tile<true, XLD>(ego, pos, t, pix0, xT);

    // ---- P0: demand MLP h1 = relu(w_d1 @ dem + b_d1) -> h1T (pixel-major bf16) ----
    {
        const int hid0 = 2 * l;  // covers hid 0..127 across 64 lanes (waves redundant? no: l is 0..63 per wave)
        // note: each wave covers all 64 hid-pairs? l=t&63 -> all 4 waves duplicate. Restrict: waves split pixels.
        const float w10 = w_d1[hid0 * 3 + 0], w11 = w_d1[hid0 * 3 + 1], w12 = w_d1[hid0 * 3 + 2];
        const float w20 = w_d1[hid0 * 3 + 3], w21 = w_d1[hid0 * 3 + 4], w22 = w_d1[hid0 * 3 + 5];
        const float bb0 = b_d1[hid0], bb1 = b_d1[hid0 + 1];
#pragma unroll
        for (int k = 0; k < 16; ++k) {
            const int p = (t >> 6) + 4 * k;  // wave-uniform pixel
            float d0 = dem[pix0 + p];
            float d1 = dem[P + pix0 + p];
            float d2v = dem[2 * P + pix0 + p];
            float h0 = fmaxf(bb0 + w10 * d0 + w11 * d1 + w12 * d2v, 0.0f);
            float h1v = fmaxf(bb1 + w20 * d0 + w21 * d1 + w22 * d2v, 0.0f);
            *reinterpret_cast<unsigned*>(&h1T[p][hid0]) = (unsigned)f2b(h0) | ((unsigned)f2b(h1v) << 16);
        }
    }
    __syncthreads();

    f32x4 acc[4][4];

    // ---- P1: qs = (w_d2 @ h1 + b_d2) + (ego + pos), written back to xT as bf16 ----
#pragma unroll
    for (int mi = 0; mi < 4; ++mi) {
        f32x4 bb = *reinterpret_cast<const f32x4*>(b_d2 + w * 64 + mi * 16 + q * 4);
#pragma unroll
        for (int ni = 0; ni < 4; ++ni) acc[mi][ni] = bb;
    }
    gemm16<HID, HLD>(wbf + OFF_WD2, h1T, w, a, q, acc);
#pragma unroll
    for (int mi = 0; mi < 4; ++mi) {
        const int row = w * 64 + mi * 16 + q * 4;
#pragma unroll
        for (int ni = 0; ni < 4; ++ni) {
            const int pix = ni * 16 + a;
            unsigned* cell = reinterpret_cast<unsigned*>(&xT[pix][row]);
            unsigned e0 = cell[0], e1 = cell[1];
            float o0 = acc[mi][ni][0] + b2f(e0 & 0xFFFFu);
            float o1 = acc[mi][ni][1] + b2f(e0 >> 16);
            float o2 = acc[mi][ni][2] + b2f(e1 & 0xFFFFu);
            float o3 = acc[mi][ni][3] + b2f(e1 >> 16);
            cell[0] = (unsigned)f2b(o0) | ((unsigned)f2b(o1) << 16);
            cell[1] = (unsigned)f2b(o2) | ((unsigned)f2b(o3) << 16);
        }
    }
    __syncthreads();

    // ---- P2: q = wq @ qs + bq, packed to bf16 in registers ----
#pragma unroll
    for (int mi = 0; mi < 4; ++mi) {
        f32x4 bb = *reinterpret_cast<const f32x4*>(bq + w * 64 + mi * 16 + q * 4);
#pragma unroll
        for (int ni = 0; ni < 4; ++ni) acc[mi][ni] = bb;
    }
    gemm16<C, XLD>(wbf + OFF_WQ, xT, w, a, q, acc);
    unsigned qpk[4][4][2];
#pragma unroll
    for (int mi = 0; mi < 4; ++mi)
#pragma unroll
        for (int ni = 0; ni < 4; ++ni) {
            qpk[mi][ni][0] = (unsigned)f2b(acc[mi][ni][0]) | ((unsigned)f2b(acc[mi][ni][1]) << 16);
            qpk[mi][ni][1] = (unsigned)f2b(acc[mi][ni][2]) | ((unsigned)f2b(acc[mi][ni][3]) << 16);
        }

    // ---- P3 pass A: scores over collaborators ----
    float sc[2][4][4];
#pragma unroll
    for (int n = 0; n < 4; ++n) {
        __syncthreads();
        stage_tile<false, XLD>(col + (size_t)n * C * P, nullptr, t, pix0, xT);
        __syncthreads();
#pragma unroll
        for (int mi = 0; mi < 4; ++mi) {
            f32x4 bb = *reinterpret_cast<const f32x4*>(bk + w * 64 + mi * 16 + q * 4);
#pragma unroll
            for (int ni = 0; ni < 4; ++ni) acc[mi][ni] = bb;
        }
        gemm16<C, XLD>(wbf + OFF_WK, xT, w, a, q, acc);
#pragma unroll
        for (int hs = 0; hs < 2; ++hs)
#pragma unroll
            for (int ni = 0; ni < 4; ++ni) {
                float ps = 0.0f;
#pragma unroll
                for (int mh = 0; mh < 2; ++mh) {
                    const int mi = hs * 2 + mh;
                    const unsigned u0 = qpk[mi][ni][0], u1 = qpk[mi][ni][1];
                    ps += b2f(u0 & 0xFFFFu) * acc[mi][ni][0];
                    ps += b2f(u0 >> 16)     * acc[mi][ni][1];
                    ps += b2f(u1 & 0xFFFFu) * acc[mi][ni][2];
                    ps += b2f(u1 >> 16)     * acc[mi][ni][3];
                }
                ps += __shfl_xor(ps, 16);
                ps += __shfl_xor(ps, 32);
                sc[hs][ni][n] = ps * 0.17677669529663687f;  // 1/sqrt(32)
            }
    }

    // ---- P4: softmax over the 4 collaborators (in-register) ----
#pragma unroll
    for (int hs = 0; hs < 2; ++hs)
#pragma unroll
        for (int ni = 0; ni < 4; ++ni) {
            float s0 = sc[hs][ni][0], s1 = sc[hs][ni][1], s2 = sc[hs][ni][2], s3 = sc[hs][ni][3];
            float mx = fmaxf(fmaxf(s0, s1), fmaxf(s2, s3));
            float e0 = __expf(s0 - mx), e1 = __expf(s1 - mx), e2 = __expf(s2 - mx), e3 = __expf(s3 - mx);
            float inv = 1.0f / (e0 + e1 + e2 + e3);
            sc[hs][ni][0] = e0 * inv; sc[hs][ni][1] = e1 * inv;
            sc[hs][ni][2] = e2 * inv; sc[hs][ni][3] = e3 * inv;
        }

    // ---- P5 pass B: ao = sum_n attn_n * (wv @ col_n + bv) ----
    f32x4 ao[4][4];
    {
        const f32x4 z = {0.0f, 0.0f, 0.0f, 0.0f};
#pragma unroll
        for (int mi = 0; mi < 4; ++mi)
#pragma unroll
            for (int ni = 0; ni < 4; ++ni) ao[mi][ni] = z;
    }
#pragma unroll
    for (int n = 0; n < 4; ++n) {
        __syncthreads();
        stage_tile<false, XLD>(col + (size_t)n * C * P, nullptr, t, pix0, xT);
        __syncthreads();
#pragma unroll
        for (int mi = 0; mi < 4; ++mi) {
            f32x4 bb = *reinterpret_cast<const f32x4*>(bv + w * 64 + mi * 16 + q * 4);
#pragma unroll
            for (int ni = 0; ni < 4; ++ni) acc[mi][ni] = bb;
        }
        gemm16<C, XLD>(wbf + OFF_WV, xT, w, a, q, acc);
#pragma unroll
        for (int mi = 0; mi < 4; ++mi)
#pragma unroll
            for (int ni = 0; ni < 4; ++ni) {
                const float wn = sc[mi >> 1][ni][n];
                ao[mi][ni] += wn * acc[mi][ni];
            }
    }

    // ---- P6: out = wo @ ao + bo ----
    __syncthreads();
#pragma unroll
    for (int mi = 0; mi < 4; ++mi) {
        const int row = w * 64 + mi * 16 + q * 4;
#pragma unroll
        for (int ni = 0; ni < 4; ++ni) {
            unsigned* cell = reinterpret_cast<unsigned*>(&xT[ni * 16 + a][row]);
            cell[0] = (unsigned)f2b(ao[mi][ni][0]) | ((unsigned)f2b(ao[mi][ni][1]) << 16);
            cell[1] = (unsigned)f2b(ao[mi][ni][2]) | ((unsigned)f2b(ao[mi][ni][3]) << 16);
        }
    }
    __syncthreads();
#pragma unroll
    for (int mi = 0; mi < 4; ++mi) {
        f32x4 bb = *reinterpret_cast<const f32x4*>(bo + w * 64 + mi * 16 + q * 4);
#pragma unroll
        for (int ni = 0; ni < 4; ++ni) acc[mi][ni] = bb;
    }
    gemm16<C, XLD>(wbf + OFF_WO, xT, w, a, q, acc);
#pragma unroll
    for (int mi = 0; mi < 4; ++mi) {
        const int row = w * 64 + mi * 16 + q * 4;
#pragma unroll
        for (int ni = 0; ni < 4; ++ni) {
            const int pix = pix0 + ni * 16 + a;
#pragma unroll
            for (int r = 0; r < 4; ++r)
                out[(size_t)(row + r) * P + pix] = acc[mi][ni][r];
        }
    }
}

extern "C" void kernel_launch(void* const* d_in, const int* in_sizes, int n_in,
                              void* d_out, int out_size, void* d_ws, size_t ws_size,
                              hipStream_t stream) {
    const float* ego  = (const float*)d_in[0];
    const float* dem  = (const float*)d_in[1];
    const float* col  = (const float*)d_in[2];
    const float* w_d1 = (const float*)d_in[3];
    const float* b_d1 = (const float*)d_in[4];
    const float* w_d2 = (const float*)d_in[5];
    const float* b_d2 = (const float*)d_in[6];
    const float* wq   = (const float*)d_in[7];
    const float* bq   = (const float*)d_in[8];
    const float* wk   = (const float*)d_in[9];
    const float* bk   = (const float*)d_in[10];
    const float* wv   = (const float*)d_in[11];
    const float* bv   = (const float*)d_in[12];
    const float* wo   = (const float*)d_in[13];
    const float* bo   = (const float*)d_in[14];
    const float* pos  = (const float*)d_in[15];
    float* out = (float*)d_out;
    unsigned short* wbf = (unsigned short*)d_ws;

    hipLaunchKernelGGL(cvt_weights, dim3((W_TOTAL + 255) / 256), dim3(256), 0, stream,
                       wq, wk, wv, wo, w_d2, wbf);
    hipLaunchKernelGGL(dca_mfma, dim3(P / BN), dim3(256), 0, stream,
                       ego, dem, col, w_d1, b_d1, b_d2, bq, bk, bv, bo, pos, wbf, out);
}

// Round 4
// 426.542 us; speedup vs baseline: 9.5676x; 1.3478x over previous
//
#include <hip/hip_runtime.h>

typedef __attribute__((ext_vector_type(8))) short short8;
typedef __attribute__((ext_vector_type(4))) float f32x4;

constexpr int C   = 256;     // MODEL_DIM
constexpr int HID = 128;
constexpr int P   = 32768;   // H*W
constexpr int BN  = 64;      // pixels per block
constexpr int XLD = 280;     // xT row len (bf16): 560B rows -> 16B aligned, 2-way banks on b128
constexpr int HLD = 136;     // h1T row len: 272B rows

// ws layout (ushort/bf16 elements)
constexpr unsigned OFF_WQ  = 0;
constexpr unsigned OFF_WK  = 65536;
constexpr unsigned OFF_WV  = 131072;
constexpr unsigned OFF_WO  = 196608;
constexpr unsigned OFF_WD2 = 262144;
constexpr unsigned W_TOTAL = 294912;

__device__ __forceinline__ unsigned f2b(float x) {           // f32 -> bf16 bits (RNE)
    unsigned u = __float_as_uint(x);
    return (u + 0x7FFFu + ((u >> 16) & 1u)) >> 16;
}
__device__ __forceinline__ float b2f(unsigned u) {           // bf16 bits (low 16) -> f32
    return __uint_as_float(u << 16);
}

__global__ void cvt_weights(const float* __restrict__ wq, const float* __restrict__ wk,
                            const float* __restrict__ wv, const float* __restrict__ wo,
                            const float* __restrict__ wd2, unsigned short* __restrict__ dst) {
    unsigned i = blockIdx.x * 256 + threadIdx.x;
    if (i >= W_TOTAL) return;
    float v;
    if (i < OFF_WK)       v = wq[i];
    else if (i < OFF_WV)  v = wk[i - OFF_WK];
    else if (i < OFF_WO)  v = wv[i - OFF_WV];
    else if (i < OFF_WD2) v = wo[i - OFF_WO];
    else                  v = wd2[i - OFF_WD2];
    dst[i] = (unsigned short)f2b(v);
}

// acc[mi][ni] += W[row0+mi*16+..][k] * B[ni*16+..][k]  (both row-major over k)
template <int K, int LD, int MI>
__device__ __forceinline__ void gemmW(const unsigned short* __restrict__ W,
                                      const unsigned short (&B)[BN][LD],
                                      int row0, int a, int q, f32x4 (*acc)[4]) {
#pragma unroll
    for (int ks = 0; ks < K / 32; ++ks) {
        const int kb = ks * 32 + q * 8;
        short8 af[MI], bf[4];
#pragma unroll
        for (int mi = 0; mi < MI; ++mi)
            af[mi] = *reinterpret_cast<const short8*>(W + (size_t)(row0 + mi * 16 + a) * K + kb);
#pragma unroll
        for (int ni = 0; ni < 4; ++ni)
            bf[ni] = *reinterpret_cast<const short8*>(&B[ni * 16 + a][kb]);
#pragma unroll
        for (int mi = 0; mi < MI; ++mi)
#pragma unroll
            for (int ni = 0; ni < 4; ++ni)
                acc[mi][ni] = __builtin_amdgcn_mfma_f32_16x16x32_bf16(af[mi], bf[ni], acc[mi][ni], 0, 0, 0);
    }
}

// stage f32 [C][P] tile (optionally + second source) -> bf16 pixel-major LDS (512 threads)
template <bool ADD>
__device__ __forceinline__ void stage_tile(const float* __restrict__ s0,
                                           const float* __restrict__ s1,
                                           int t, int pix0, unsigned short (&X)[BN][XLD]) {
    const int cg = t >> 4;        // 0..31 -> channel pair
    const int pb = 4 * (t & 15);  // pixel base
#pragma unroll
    for (int k = 0; k < 4; ++k) {
        const int c = 2 * cg + 64 * k;
        float4 ra = *reinterpret_cast<const float4*>(s0 + (size_t)c * P + pix0 + pb);
        float4 rb = *reinterpret_cast<const float4*>(s0 + (size_t)(c + 1) * P + pix0 + pb);
        if constexpr (ADD) {
            float4 ta = *reinterpret_cast<const float4*>(s1 + (size_t)c * P + pix0 + pb);
            float4 tb = *reinterpret_cast<const float4*>(s1 + (size_t)(c + 1) * P + pix0 + pb);
            ra.x += ta.x; ra.y += ta.y; ra.z += ta.z; ra.w += ta.w;
            rb.x += tb.x; rb.y += tb.y; rb.z += tb.z; rb.w += tb.w;
        }
        const float va[4] = {ra.x, ra.y, ra.z, ra.w};
        const float vb[4] = {rb.x, rb.y, rb.z, rb.w};
#pragma unroll
        for (int pi = 0; pi < 4; ++pi) {
            unsigned pk = f2b(va[pi]) | (f2b(vb[pi]) << 16);
            *reinterpret_cast<unsigned*>(&X[pb + pi][c]) = pk;
        }
    }
}

__global__ __launch_bounds__(512, 1) void dca_mfma(
    const float* __restrict__ ego, const float* __restrict__ dem,
    const float* __restrict__ col,
    const float* __restrict__ w_d1, const float* __restrict__ b_d1,
    const float* __restrict__ b_d2, const float* __restrict__ bq,
    const float* __restrict__ bk, const float* __restrict__ bv,
    const float* __restrict__ bo, const float* __restrict__ pos,
    const unsigned short* __restrict__ wbf, float* __restrict__ out)
{
    __shared__ __align__(16) unsigned short xT[BN][XLD];
    __shared__ __align__(16) unsigned short h1T[BN][HLD];

    const int t = threadIdx.x;
    const int w = t >> 6;    // wave 0..7 == head w, owns channels [32w, 32w+32)
    const int l = t & 63;
    const int a = l & 15;
    const int q = l >> 4;
    const int row0 = w * 32;
    const int pix0 = blockIdx.x * BN;

    // ---- stage bf16(ego + pos) ----
    stage_tile<true>(ego, pos, t, pix0, xT);

    // ---- demand MLP: h1 = relu(w_d1 @ dem + b_d1) -> h1T ----
    {
        const int hid0 = 2 * l;
        const float w10 = w_d1[hid0 * 3 + 0], w11 = w_d1[hid0 * 3 + 1], w12 = w_d1[hid0 * 3 + 2];
        const float w20 = w_d1[hid0 * 3 + 3], w21 = w_d1[hid0 * 3 + 4], w22 = w_d1[hid0 * 3 + 5];
        const float bb0 = b_d1[hid0], bb1 = b_d1[hid0 + 1];
#pragma unroll
        for (int k = 0; k < 8; ++k) {
            const int p = w + 8 * k;  // wave-uniform pixel
            float d0 = dem[pix0 + p];
            float d1 = dem[P + pix0 + p];
            float d2v = dem[2 * P + pix0 + p];
            float h0 = fmaxf(bb0 + w10 * d0 + w11 * d1 + w12 * d2v, 0.0f);
            float h1v = fmaxf(bb1 + w20 * d0 + w21 * d1 + w22 * d2v, 0.0f);
            *reinterpret_cast<unsigned*>(&h1T[p][hid0]) = f2b(h0) | (f2b(h1v) << 16);
        }
    }
    __syncthreads();

    f32x4 acc[2][4];

    // ---- P1: qs = (w_d2 @ h1 + b_d2) + (ego + pos), back into xT ----
#pragma unroll
    for (int mi = 0; mi < 2; ++mi) {
        f32x4 bb = *reinterpret_cast<const f32x4*>(b_d2 + row0 + mi * 16 + q * 4);
#pragma unroll
        for (int ni = 0; ni < 4; ++ni) acc[mi][ni] = bb;
    }
    gemmW<HID, HLD, 2>(wbf + OFF_WD2, h1T, row0, a, q, acc);
#pragma unroll
    for (int mi = 0; mi < 2; ++mi) {
        const int cb = row0 + mi * 16 + q * 4;
#pragma unroll
        for (int ni = 0; ni < 4; ++ni) {
            unsigned* cell = reinterpret_cast<unsigned*>(&xT[ni * 16 + a][cb]);
            unsigned e0 = cell[0], e1 = cell[1];
            float o0 = acc[mi][ni][0] + b2f(e0 & 0xFFFFu);
            float o1 = acc[mi][ni][1] + b2f(e0 >> 16);
            float o2 = acc[mi][ni][2] + b2f(e1 & 0xFFFFu);
            float o3 = acc[mi][ni][3] + b2f(e1 >> 16);
            cell[0] = f2b(o0) | (f2b(o1) << 16);
            cell[1] = f2b(o2) | (f2b(o3) << 16);
        }
    }
    __syncthreads();

    // ---- P2: q = wq @ qs + bq (this wave's head only), packed bf16 in regs ----
#pragma unroll
    for (int mi = 0; mi < 2; ++mi) {
        f32x4 bb = *reinterpret_cast<const f32x4*>(bq + row0 + mi * 16 + q * 4);
#pragma unroll
        for (int ni = 0; ni < 4; ++ni) acc[mi][ni] = bb;
    }
    gemmW<C, XLD, 2>(wbf + OFF_WQ, xT, row0, a, q, acc);
    unsigned qpk[2][4][2];
#pragma unroll
    for (int mi = 0; mi < 2; ++mi)
#pragma unroll
        for (int ni = 0; ni < 4; ++ni) {
            qpk[mi][ni][0] = f2b(acc[mi][ni][0]) | (f2b(acc[mi][ni][1]) << 16);
            qpk[mi][ni][1] = f2b(acc[mi][ni][2]) | (f2b(acc[mi][ni][3]) << 16);
        }

    // ---- fused k/v passes with online softmax; col staged ONCE per n ----
    f32x4 ao[2][4];
    float mrun[4], lrun[4];
#pragma unroll
    for (int ni = 0; ni < 4; ++ni) { mrun[ni] = -3.0e38f; lrun[ni] = 0.0f; }
    {
        const f32x4 z = {0.0f, 0.0f, 0.0f, 0.0f};
#pragma unroll
        for (int mi = 0; mi < 2; ++mi)
#pragma unroll
            for (int ni = 0; ni < 4; ++ni) ao[mi][ni] = z;
    }
#pragma unroll
    for (int n = 0; n < 4; ++n) {
        __syncthreads();
        stage_tile<false>(col + (size_t)n * C * P, nullptr, t, pix0, xT);
        __syncthreads();
        // k-GEMM
#pragma unroll
        for (int mi = 0; mi < 2; ++mi) {
            f32x4 bb = *reinterpret_cast<const f32x4*>(bk + row0 + mi * 16 + q * 4);
#pragma unroll
            for (int ni = 0; ni < 4; ++ni) acc[mi][ni] = bb;
        }
        gemmW<C, XLD, 2>(wbf + OFF_WK, xT, row0, a, q, acc);
        // scores: dot(q, k) over this head's 32 channels
        float s[4];
#pragma unroll
        for (int ni = 0; ni < 4; ++ni) {
            float ps = 0.0f;
#pragma unroll
            for (int mi = 0; mi < 2; ++mi) {
                const unsigned u0 = qpk[mi][ni][0], u1 = qpk[mi][ni][1];
                ps += b2f(u0 & 0xFFFFu) * acc[mi][ni][0];
                ps += b2f(u0 >> 16)     * acc[mi][ni][1];
                ps += b2f(u1 & 0xFFFFu) * acc[mi][ni][2];
                ps += b2f(u1 >> 16)     * acc[mi][ni][3];
            }
            ps += __shfl_xor(ps, 16);
            ps += __shfl_xor(ps, 32);
            s[ni] = ps * 0.17677669529663687f;  // 1/sqrt(32)
        }
        // v-GEMM (reuses acc registers)
#pragma unroll
        for (int mi = 0; mi < 2; ++mi) {
            f32x4 bb = *reinterpret_cast<const f32x4*>(bv + row0 + mi * 16 + q * 4);
#pragma unroll
            for (int ni = 0; ni < 4; ++ni) acc[mi][ni] = bb;
        }
        gemmW<C, XLD, 2>(wbf + OFF_WV, xT, row0, a, q, acc);
        // online softmax accumulate
#pragma unroll
        for (int ni = 0; ni < 4; ++ni) {
            float mnew  = fmaxf(mrun[ni], s[ni]);
            float alpha = __expf(mrun[ni] - mnew);
            float pp    = __expf(s[ni] - mnew);
            lrun[ni] = lrun[ni] * alpha + pp;
            mrun[ni] = mnew;
#pragma unroll
            for (int mi = 0; mi < 2; ++mi)
                ao[mi][ni] = alpha * ao[mi][ni] + pp * acc[mi][ni];
        }
    }
    // normalize
#pragma unroll
    for (int ni = 0; ni < 4; ++ni) {
        float inv = 1.0f / lrun[ni];
#pragma unroll
        for (int mi = 0; mi < 2; ++mi) ao[mi][ni] *= inv;
    }

    // ---- stage attention output, o-GEMM ----
    __syncthreads();
#pragma unroll
    for (int mi = 0; mi < 2; ++mi) {
        const int cb = row0 + mi * 16 + q * 4;
#pragma unroll
        for (int ni = 0; ni < 4; ++ni) {
            unsigned* cell = reinterpret_cast<unsigned*>(&xT[ni * 16 + a][cb]);
            cell[0] = f2b(ao[mi][ni][0]) | (f2b(ao[mi][ni][1]) << 16);
            cell[1] = f2b(ao[mi][ni][2]) | (f2b(ao[mi][ni][3]) << 16);
        }
    }
    __syncthreads();
#pragma unroll
    for (int mi = 0; mi < 2; ++mi) {
        f32x4 bb = *reinterpret_cast<const f32x4*>(bo + row0 + mi * 16 + q * 4);
#pragma unroll
        for (int ni = 0; ni < 4; ++ni) acc[mi][ni] = bb;
    }
    gemmW<C, XLD, 2>(wbf + OFF_WO, xT, row0, a, q, acc);
#pragma unroll
    for (int mi = 0; mi < 2; ++mi) {
        const int cb = row0 + mi * 16 + q * 4;
#pragma unroll
        for (int ni = 0; ni < 4; ++ni) {
            const int pix = pix0 + ni * 16 + a;
#pragma unroll
            for (int r = 0; r < 4; ++r)
                out[(size_t)(cb + r) * P + pix] = acc[mi][ni][r];
        }
    }
}

extern "C" void kernel_launch(void* const* d_in, const int* in_sizes, int n_in,
                              void* d_out, int out_size, void* d_ws, size_t ws_size,
                              hipStream_t stream) {
    const float* ego  = (const float*)d_in[0];
    const float* dem  = (const float*)d_in[1];
    const float* col  = (const float*)d_in[2];
    const float* w_d1 = (const float*)d_in[3];
    const float* b_d1 = (const float*)d_in[4];
    const float* w_d2 = (const float*)d_in[5];
    const float* b_d2 = (const float*)d_in[6];
    const float* wq   = (const float*)d_in[7];
    const float* bq   = (const float*)d_in[8];
    const float* wk   = (const float*)d_in[9];
    const float* bk   = (const float*)d_in[10];
    const float* wv   = (const float*)d_in[11];
    const float* bv   = (const float*)d_in[12];
    const float* wo   = (const float*)d_in[13];
    const float* bo   = (const float*)d_in[14];
    const float* pos  = (const float*)d_in[15];
    float* out = (float*)d_out;
    unsigned short* wbf = (unsigned short*)d_ws;

    hipLaunchKernelGGL(cvt_weights, dim3((W_TOTAL + 255) / 256), dim3(256), 0, stream,
                       wq, wk, wv, wo, w_d2, wbf);
    hipLaunchKernelGGL(dca_mfma, dim3(P / BN), dim3(512), 0, stream,
                       ego, dem, col, w_d1, b_d1, b_d2, bq, bk, bv, bo, pos, wbf, out);
}